// Round 4
// baseline (103.361 us; speedup 1.0000x reference)
//
#include <hip/hip_runtime.h>

#define NROWS 4096
#define NCOLS 10000
#define NLAT  64
#define NCOLG 2500      /* NCOLS / 4 */
#define TPB   256
#define NRC   128       /* row chunks in kernel 1 */
#define RPC   32        /* rows per chunk = NROWS / NRC */
#define NSLICE 16       /* chunk slices in kernel 2 */
#define CPS   (NRC / NSLICE)   /* 8 chunks per slice */
#define NCB   40        /* column blocks in kernel 2 */
#define CPB   250       /* columns per block */
#define NBLK2 (NCB * NSLICE)   /* 640 fold blocks = 2.5/CU */

// Kernel 1: single streaming pass over X (163.84 MB). Thread owns 4
// consecutive columns (float4 coalesced, 1024B/wave); block-row y does 32
// rows; partial colsum + colsum^2 to fixed slots (deterministic).
// Grid (10, 128) = 1280 blocks = 5/CU exactly. Also zeroes the fold counter.
__global__ void colsum_partials(const float* __restrict__ X,
                                float* __restrict__ ps,
                                float* __restrict__ ps2,
                                unsigned int* __restrict__ counter) {
    if (blockIdx.x == 0 && blockIdx.y == 0 && threadIdx.x == 0) *counter = 0u;
    int jg = blockIdx.x * TPB + threadIdx.x;          // column group (4 cols)
    if (jg >= NCOLG) return;

    float s0 = 0.f, s1 = 0.f, s2 = 0.f, s3 = 0.f;
    float q0 = 0.f, q1 = 0.f, q2 = 0.f, q3 = 0.f;
    const float* base = X + (size_t)blockIdx.y * RPC * NCOLS + (size_t)jg * 4;
    #pragma unroll 8
    for (int r = 0; r < RPC; ++r) {
        float4 v = *reinterpret_cast<const float4*>(base);
        base += NCOLS;
        s0 += v.x; s1 += v.y; s2 += v.z; s3 += v.w;
        q0 += v.x * v.x; q1 += v.y * v.y; q2 += v.z * v.z; q3 += v.w * v.w;
    }
    size_t o = (size_t)blockIdx.y * NCOLS + (size_t)jg * 4;
    *reinterpret_cast<float4*>(ps  + o) = make_float4(s0, s1, s2, s3);
    *reinterpret_cast<float4*>(ps2 + o) = make_float4(q0, q1, q2, q3);
}

// Kernel 2: distributed fold + q + t partials + fused finalize.
// Block (cb, sl) folds 8 chunks for its 250 columns, emits q-partial and
// t[64]-partial into TRANSPOSED tpT[f][bid] (f=64 row holds q). The last
// block to finish (atomic ticket) does the final fixed-order reduction —
// result is independent of which block wins -> deterministic.
__global__ void fold_q_t_final(const float* __restrict__ ps,
                               const float* __restrict__ ps2,
                               const float* __restrict__ V,
                               float* __restrict__ tpT,
                               unsigned int* __restrict__ counter,
                               float* __restrict__ out) {
    int cb = blockIdx.x;               // 0..39   column block
    int sl = blockIdx.y;               // 0..15   chunk slice
    int j  = threadIdx.x;
    int col = cb * CPB + j;
    bool active = (j < CPB);

    float s = 0.f, s2 = 0.f, q = 0.f;
    if (active) {
        int c0 = sl * CPS;
        #pragma unroll
        for (int c = c0; c < c0 + CPS; ++c) {
            s  += ps [(size_t)c * NCOLS + col];
            s2 += ps2[(size_t)c * NCOLS + col];
        }
        float w2 = 0.f;
        const float4* vp = reinterpret_cast<const float4*>(V + (size_t)col * NLAT);
        #pragma unroll
        for (int k = 0; k < NLAT / 4; ++k) {
            float4 v = vp[k];
            w2 += v.x * v.x + v.y * v.y + v.z * v.z + v.w * v.w;
        }
        q = s2 * w2;
    }

    // q: butterfly within wave, LDS across the 4 waves
    #pragma unroll
    for (int st = 1; st < 64; st <<= 1) q += __shfl_xor(q, st, 64);

    __shared__ float lds_q[4];
    __shared__ float lds_s[TPB];
    __shared__ float lds_t[4][NLAT];
    int lane = threadIdx.x & 63, w = threadIdx.x >> 6;
    if (lane == 0) lds_q[w] = q;
    lds_s[j] = active ? s : 0.f;
    __syncthreads();

    // t-partial: lane owns latent f; wave w strides the block's 250 columns.
    float acc = 0.f;
    const float* Vb = V + (size_t)cb * CPB * NLAT;
    for (int c = w; c < CPB; c += 4)
        acc += lds_s[c] * Vb[(size_t)c * NLAT + lane];
    lds_t[w][lane] = acc;
    __syncthreads();

    int bid = sl * NCB + cb;
    if (threadIdx.x < NLAT)
        tpT[(size_t)threadIdx.x * NBLK2 + bid] =
            lds_t[0][threadIdx.x] + lds_t[1][threadIdx.x] +
            lds_t[2][threadIdx.x] + lds_t[3][threadIdx.x];
    if (threadIdx.x == 0)
        tpT[(size_t)NLAT * NBLK2 + bid] = lds_q[0] + lds_q[1] + lds_q[2] + lds_q[3];

    // last-block finalize
    __threadfence();
    __syncthreads();
    __shared__ unsigned int is_last;
    if (threadIdx.x == 0) is_last = (atomicAdd(counter, 1u) == NBLK2 - 1) ? 1u : 0u;
    __syncthreads();
    if (!is_last) return;
    __threadfence();

    // 256 threads: f = tid&63, seg = tid>>6; each sums 160 consecutive floats
    int f = threadIdx.x & 63, seg = threadIdx.x >> 6;
    const float4* row = reinterpret_cast<const float4*>(
        tpT + (size_t)f * NBLK2 + seg * (NBLK2 / 4));
    float tf = 0.f;
    #pragma unroll 8
    for (int i = 0; i < NBLK2 / 16; ++i) {       // 40 float4s
        float4 v = row[i];
        tf += v.x + v.y + v.z + v.w;
    }
    __shared__ float red[4][NLAT];
    red[seg][f] = tf;
    __syncthreads();
    if (threadIdx.x < NLAT) {
        float t = red[0][f] + red[1][f] + red[2][f] + red[3][f];
        const float* qrow = tpT + (size_t)NLAT * NBLK2;
        float qf = 0.f;
        #pragma unroll
        for (int b = 0; b < NBLK2 / 64; ++b) qf += qrow[f * (NBLK2 / 64) + b];
        float d = t * t - qf;
        #pragma unroll
        for (int st = 1; st < 64; st <<= 1) d += __shfl_xor(d, st, 64);
        if (f == 0) out[0] = 0.5f * d;
    }
}

extern "C" void kernel_launch(void* const* d_in, const int* in_sizes, int n_in,
                              void* d_out, int out_size, void* d_ws, size_t ws_size,
                              hipStream_t stream) {
    const float* X = (const float*)d_in[0];   // [4096, 10000] f32
    const float* V = (const float*)d_in[1];   // [10000, 64]  f32
    float* out = (float*)d_out;               // scalar f32

    float* ps    = (float*)d_ws;                       // [NRC][NCOLS]
    float* ps2   = ps  + (size_t)NRC * NCOLS;          // [NRC][NCOLS]
    float* tpT   = ps2 + (size_t)NRC * NCOLS;          // [NLAT+1][NBLK2]
    unsigned int* counter = (unsigned int*)(tpT + (size_t)(NLAT + 1) * NBLK2);

    colsum_partials<<<dim3((NCOLG + TPB - 1) / TPB, NRC), TPB, 0, stream>>>(
        X, ps, ps2, counter);
    fold_q_t_final<<<dim3(NCB, NSLICE), TPB, 0, stream>>>(
        ps, ps2, V, tpT, counter, out);
}

// Round 5
// 69.630 us; speedup vs baseline: 1.4844x; 1.4844x over previous
//
#include <hip/hip_runtime.h>

#define NROWS 4096
#define NCOLS 10000
#define NLAT  64
#define TPB   256
#define COLB  1024              /* columns per block = TPB * 4 */
#define NBX   10                /* ceil(NCOLS / COLB) */
#define NRC   128               /* row chunks */
#define RPC   32                /* rows per chunk = NROWS / NRC */
#define NBLK  (NBX * NRC)       /* 1280 blocks = 5/CU exactly */
#define TPB2  1024

// Kernel 1: single streaming pass over X (163.84 MB) with the V-matvec fused.
// Phase A: thread owns 4 consecutive columns (float4 coalesced, 1024B/wave),
//          accumulates colsum s and colsum^2 s2 over its 32-row chunk.
// Phase B: stage s,s2 in LDS; wave-parallel matvec vs V (L2-resident):
//          lane = latent f, waves stride columns; accumulate
//          t_part[f] += s[c]*V[c,f]  and  q_part += s2[c]*V[c,f]^2.
// Both q and t are linear in per-chunk partials, so per-block partials sum
// exactly. Fixed reduction order -> deterministic. No global fences/atomics
// (R4 lesson: 640 device-scope threadfences cost ~50us on 8 XCDs).
__global__ __launch_bounds__(TPB) void pass_x(const float* __restrict__ X,
                                              const float* __restrict__ V,
                                              float* __restrict__ tpart,
                                              float* __restrict__ qpart) {
    const int bx = blockIdx.x;            // column block 0..9
    const int by = blockIdx.y;            // row chunk  0..127
    const int tid = threadIdx.x;
    const int col0 = bx * COLB;
    const int jg = col0 + tid * 4;        // first of this thread's 4 columns

    float s0 = 0.f, s1 = 0.f, s2 = 0.f, s3 = 0.f;
    float q0 = 0.f, q1 = 0.f, q2 = 0.f, q3 = 0.f;
    if (jg < NCOLS) {                     // NCOLS % 4 == 0, so all-4 valid
        const float* p = X + (size_t)by * RPC * NCOLS + jg;
        #pragma unroll 8
        for (int r = 0; r < RPC; ++r) {
            float4 v = *reinterpret_cast<const float4*>(p);
            p += NCOLS;
            s0 += v.x; s1 += v.y; s2 += v.z; s3 += v.w;
            q0 += v.x * v.x; q1 += v.y * v.y; q2 += v.z * v.z; q3 += v.w * v.w;
        }
    }

    __shared__ float lds_s [COLB];
    __shared__ float lds_s2[COLB];
    *reinterpret_cast<float4*>(&lds_s [tid * 4]) = make_float4(s0, s1, s2, s3);
    *reinterpret_cast<float4*>(&lds_s2[tid * 4]) = make_float4(q0, q1, q2, q3);
    __syncthreads();

    const int lane = tid & 63, w = tid >> 6;
    const int cmax = (NCOLS - col0 < COLB) ? (NCOLS - col0) : COLB;
    float at = 0.f, aq = 0.f;
    #pragma unroll 4
    for (int c = w; c < cmax; c += 4) {
        float v  = V[(size_t)(col0 + c) * NLAT + lane];   // 256B/wave, L2-hit
        float sc = lds_s[c], s2c = lds_s2[c];             // LDS broadcast
        at = fmaf(sc, v, at);
        aq = fmaf(s2c, v * v, aq);
    }

    // q: butterfly within wave (sum over latents), LDS across 4 waves
    #pragma unroll
    for (int st = 1; st < 64; st <<= 1) aq += __shfl_xor(aq, st, 64);

    __shared__ float lds_t[4][NLAT];
    __shared__ float lds_q[4];
    if (lane == 0) lds_q[w] = aq;
    lds_t[w][lane] = at;
    __syncthreads();

    const int bid = by * NBX + bx;
    if (tid < NLAT)
        tpart[(size_t)bid * NLAT + tid] =
            lds_t[0][tid] + lds_t[1][tid] + lds_t[2][tid] + lds_t[3][tid];
    if (tid == 0)
        qpart[bid] = lds_q[0] + lds_q[1] + lds_q[2] + lds_q[3];
}

// Kernel 2: out = 0.5 * (sum_f t[f]^2 - q). One 1024-thread block; reads
// 333 KB of partials with coalesced 256B wave reads; fixed order.
__global__ __launch_bounds__(TPB2) void finalize(const float* __restrict__ tpart,
                                                 const float* __restrict__ qpart,
                                                 float* __restrict__ out) {
    const int tid = threadIdx.x, f = tid & 63, seg = tid >> 6;   // 16 waves
    float tf = 0.f;
    for (int b = seg; b < NBLK; b += 16)          // 80 iters, 256B/wave
        tf += tpart[(size_t)b * NLAT + f];
    __shared__ float red[16][NLAT];
    red[seg][f] = tf;

    float qa = 0.f;
    for (int b = tid; b < NBLK; b += TPB2) qa += qpart[b];
    #pragma unroll
    for (int st = 1; st < 64; st <<= 1) qa += __shfl_xor(qa, st, 64);
    __shared__ float qr[16];
    if (f == 0) qr[seg] = qa;
    __syncthreads();

    if (tid < NLAT) {
        float t = 0.f;
        #pragma unroll
        for (int s = 0; s < 16; ++s) t += red[s][tid];
        float d = t * t;
        #pragma unroll
        for (int st = 1; st < 64; st <<= 1) d += __shfl_xor(d, st, 64);
        if (tid == 0) {
            float q = 0.f;
            #pragma unroll
            for (int s = 0; s < 16; ++s) q += qr[s];
            out[0] = 0.5f * (d - q);
        }
    }
}

extern "C" void kernel_launch(void* const* d_in, const int* in_sizes, int n_in,
                              void* d_out, int out_size, void* d_ws, size_t ws_size,
                              hipStream_t stream) {
    const float* X = (const float*)d_in[0];   // [4096, 10000] f32
    const float* V = (const float*)d_in[1];   // [10000, 64]  f32
    float* out = (float*)d_out;               // scalar f32

    float* tpart = (float*)d_ws;                       // [NBLK][NLAT]
    float* qpart = tpart + (size_t)NBLK * NLAT;        // [NBLK]

    pass_x<<<dim3(NBX, NRC), TPB, 0, stream>>>(X, V, tpart, qpart);
    finalize<<<1, TPB2, 0, stream>>>(tpart, qpart, out);
}

// Round 6
// 42.809 us; speedup vs baseline: 2.4145x; 1.6265x over previous
//
#include <hip/hip_runtime.h>

#define NROWS 4096
#define NCOLS 10000
#define NLAT  64
#define NCOLG 2500              /* NCOLS / 4 */
#define TPB   256
#define NBX   10                /* column blocks in K1 */
#define NRC   128               /* row chunks: 10*128 = 1280 blocks = 5/CU */
#define RPC   32                /* rows per chunk */
#define NCB   40                /* column blocks in fold */
#define CPB   250               /* columns per fold block */
#define NSLICE 16               /* chunk slices in fold */
#define CPS   (NRC / NSLICE)    /* 8 chunks per slice */
#define NBLK2 (NCB * NSLICE)    /* 640 fold blocks */

// K1: pure streaming pass over X (163.84 MB), nothing else. Thread owns 4
// consecutive columns (float4, 1024B/wave coalesced); block-row y covers 32
// rows; writes partial colsum/colsum^2 to fixed slots. 1280 blocks = 5/CU.
__global__ __launch_bounds__(TPB) void colsum_partials(
        const float* __restrict__ X,
        float* __restrict__ ps, float* __restrict__ ps2) {
    int jg = blockIdx.x * TPB + threadIdx.x;          // column group
    if (jg >= NCOLG) return;
    const float* p = X + (size_t)blockIdx.y * RPC * NCOLS + (size_t)jg * 4;
    float s0=0.f,s1=0.f,s2=0.f,s3=0.f,q0=0.f,q1=0.f,q2=0.f,q3=0.f;
    #pragma unroll 8
    for (int r = 0; r < RPC; ++r) {
        float4 v = *reinterpret_cast<const float4*>(p);
        p += NCOLS;
        s0 += v.x; s1 += v.y; s2 += v.z; s3 += v.w;
        q0 = fmaf(v.x, v.x, q0); q1 = fmaf(v.y, v.y, q1);
        q2 = fmaf(v.z, v.z, q2); q3 = fmaf(v.w, v.w, q3);
    }
    size_t o = (size_t)blockIdx.y * NCOLS + (size_t)jg * 4;
    *reinterpret_cast<float4*>(ps  + o) = make_float4(s0, s1, s2, s3);
    *reinterpret_cast<float4*>(ps2 + o) = make_float4(q0, q1, q2, q3);
}

// K2: fold + single coalesced V sweep -> t[64]-partial and q-partial per
// block, written TRANSPOSED (tpT[f][bid]; row 64 = q). Both t and q are
// linear in chunk partials so slice-blocks sum exactly. Lane = latent f,
// V reads are 256B/wave coalesced; lds_s[c] is wave-uniform broadcast.
// All reduction orders fixed -> deterministic.
__global__ __launch_bounds__(TPB) void fold_qt(
        const float* __restrict__ ps, const float* __restrict__ ps2,
        const float* __restrict__ V, float* __restrict__ tpT) {
    const int cb = blockIdx.x;          // 0..39
    const int sl = blockIdx.y;          // 0..15
    const int tid = threadIdx.x;
    __shared__ float lds_s[CPB], lds_s2[CPB];
    if (tid < CPB) {
        const int col = cb * CPB + tid;
        float s = 0.f, s2 = 0.f;
        const int c0 = sl * CPS;
        #pragma unroll
        for (int c = c0; c < c0 + CPS; ++c) {        // coalesced 1KB runs
            s  += ps [(size_t)c * NCOLS + col];
            s2 += ps2[(size_t)c * NCOLS + col];
        }
        lds_s[tid] = s; lds_s2[tid] = s2;
    }
    __syncthreads();

    const int lane = tid & 63, w = tid >> 6;
    float at = 0.f, aq = 0.f;
    const float* Vb = V + (size_t)cb * CPB * NLAT;
    #pragma unroll 4
    for (int c = w; c < CPB; c += 4) {
        float v = Vb[(size_t)c * NLAT + lane];       // 256B/wave, L2-hit
        at = fmaf(lds_s[c], v, at);
        aq = fmaf(lds_s2[c], v * v, aq);
    }
    #pragma unroll
    for (int st = 1; st < 64; st <<= 1) aq += __shfl_xor(aq, st, 64);

    __shared__ float lt[4][NLAT];
    __shared__ float lq[4];
    lt[w][lane] = at;
    if (lane == 0) lq[w] = aq;
    __syncthreads();

    const int bid = sl * NCB + cb;                   // 0..639
    if (tid < NLAT)
        tpT[(size_t)tid * NBLK2 + bid] = lt[0][tid] + lt[1][tid]
                                       + lt[2][tid] + lt[3][tid];
    if (tid == 0)
        tpT[(size_t)NLAT * NBLK2 + bid] = lq[0] + lq[1] + lq[2] + lq[3];
}

// K3: out = 0.5*(sum_f t[f]^2 - q). 16 waves; wave w reduces contiguous
// 2.56KB rows r = w, w+16, ... (coalesced 256B steps + butterfly).
__global__ __launch_bounds__(1024) void finalize(
        const float* __restrict__ tpT, float* __restrict__ out) {
    const int tid = threadIdx.x, lane = tid & 63, w = tid >> 6;
    __shared__ float red[NLAT + 1];
    for (int r = w; r < NLAT + 1; r += 16) {
        const float* row = tpT + (size_t)r * NBLK2;
        float a = 0.f;
        #pragma unroll
        for (int i = 0; i < NBLK2 / 64; ++i) a += row[i * 64 + lane];
        #pragma unroll
        for (int st = 1; st < 64; st <<= 1) a += __shfl_xor(a, st, 64);
        if (lane == 0) red[r] = a;
    }
    __syncthreads();
    if (w == 0) {
        float t = red[lane];
        float d = t * t;
        #pragma unroll
        for (int st = 1; st < 64; st <<= 1) d += __shfl_xor(d, st, 64);
        if (lane == 0) out[0] = 0.5f * (d - red[NLAT]);
    }
}

extern "C" void kernel_launch(void* const* d_in, const int* in_sizes, int n_in,
                              void* d_out, int out_size, void* d_ws, size_t ws_size,
                              hipStream_t stream) {
    const float* X = (const float*)d_in[0];   // [4096, 10000] f32
    const float* V = (const float*)d_in[1];   // [10000, 64]  f32
    float* out = (float*)d_out;               // scalar f32

    float* ps  = (float*)d_ws;                         // [NRC][NCOLS]
    float* ps2 = ps  + (size_t)NRC * NCOLS;            // [NRC][NCOLS]
    float* tpT = ps2 + (size_t)NRC * NCOLS;            // [NLAT+1][NBLK2]

    colsum_partials<<<dim3(NBX, NRC), TPB, 0, stream>>>(X, ps, ps2);
    fold_qt<<<dim3(NCB, NSLICE), TPB, 0, stream>>>(ps, ps2, V, tpT);
    finalize<<<1, 1024, 0, stream>>>(tpT, out);
}